// Round 12
// baseline (255.402 us; speedup 1.0000x reference)
//
#include <hip/hip_runtime.h>
#include <hip/hip_fp16.h>

// e3jLayer: per-edge equivariant tensor product + segment-sum + linear.
// Round 20: converge on best-measured geometry + VALU trim.
//   Evidence: gather pinned at 92-93us across 3 structural variants
//   (occ 49/76/71%, fetch 200/445/239MB) -> latency/VALU co-bound; half-bin
//   (R15) has lowest fetch, keep it. Build: R15 512t/CHUNK8192 was in the
//   best total (239.7); 256t fused=96us, 1024t=flat, ticket=169us -> revert.
//   New: deferred-scale accumulators (sum X0 / x1.d / x0*d+x1 / cross parts
//   in 8 regs, scale by INV_S3/INV_S2/(1/32) once at end) removes 4 mults
//   per (edge,lane); lpos LDS staging removes a per-edge global read.
// Fallback: exact 3-kernel CSR path if sizing fails.

#define F_DIM 16
#define BIN_SHIFT 6
#define BIN_NODES (1 << BIN_SHIFT)   // 64 receivers per bin
#define HALF_NODES (BIN_NODES / 2)   // 32 per gather block
#define CHUNK 8192                   // edges per build block
#define CAP_LDS 1408                 // max edges per bin-half in gather LDS
#define MAXBINS 2048

__device__ __forceinline__ float4 unpack_h4(uint2 u)
{
    __half2 h01 = *reinterpret_cast<__half2*>(&u.x);
    __half2 h23 = *reinterpret_cast<__half2*>(&u.y);
    float2 a = __half22float2(h01);
    float2 b = __half22float2(h23);
    return make_float4(a.x, a.y, b.x, b.y);
}

// accumulate one edge with DEFERRED scaling: no INV_S3/INV_S2 mults here.
//   sA  += x0            sB  += x1.d
//   s1i += x0*di + xi    cci += cross_i(x1, d)
__device__ __forceinline__ void edge_acc_d(
    float dx, float dy, float dz, const float4& fx,
    float& sA, float& sB, float& s1x, float& s1y, float& s1z,
    float& c0, float& c1, float& c2)
{
    sA += fx.x;
    sB += fx.y*dx + fx.z*dy + fx.w*dz;
    s1x += __builtin_fmaf(fx.x, dx, fx.y);
    s1y += __builtin_fmaf(fx.x, dy, fx.z);
    s1z += __builtin_fmaf(fx.x, dz, fx.w);
    c0 += fx.z*dz - fx.w*dy;
    c1 += fx.w*dx - fx.y*dz;
    c2 += fx.y*dy - fx.z*dx;
}

// ---- pack: nf->fp16 rows, pos->float4, zero binCur (one dispatch) ----------
__global__ void __launch_bounds__(256) pack_kernel(
    const float* __restrict__ pos, const float* __restrict__ nf,
    float4* __restrict__ posf4, uint2* __restrict__ nfh,
    int* __restrict__ binCur, int N, int nbins)
{
    int tid = blockIdx.x * blockDim.x + threadIdx.x;
    int total = N * F_DIM;
    if (tid < total) {
        float4 q = ((const float4*)nf)[tid];
        __half2 h01 = __floats2half2_rn(q.x, q.y);
        __half2 h23 = __floats2half2_rn(q.z, q.w);
        uint2 u;
        u.x = *reinterpret_cast<unsigned*>(&h01);
        u.y = *reinterpret_cast<unsigned*>(&h23);
        nfh[tid] = u;
    }
    if (tid < N)
        posf4[tid] = make_float4(pos[3*tid], pos[3*tid+1], pos[3*tid+2], 0.f);
    if (tid < nbins)
        binCur[tid] = 0;
}

// ---- two-pass grouped-run build @512t (R15 config): pass A histogram,
// claim cursors, pass B re-read + scatter. binCur = zero-based counts. ------
__global__ void __launch_bounds__(512) build_bins_kernel(
    const int* __restrict__ senders, const int* __restrict__ receivers,
    int* __restrict__ binCur, int* __restrict__ bins,
    int nbins, int cap, int E)
{
    __shared__ int hbase[MAXBINS];   // count, then base offset within bin
    __shared__ int hrank[MAXBINS];   // scatter tickets
    int t = threadIdx.x;
    for (int i = t; i < nbins; i += 512) { hbase[i] = 0; hrank[i] = 0; }
    __syncthreads();

    int base = blockIdx.x * CHUNK;
    int end  = base + CHUNK; if (end > E) end = E;
    if (base >= end) return;

    // pass A: histogram receiver bins
    for (int e = base + t; e < end; e += 512)
        atomicAdd(&hbase[((unsigned)receivers[e]) >> BIN_SHIFT], 1);
    __syncthreads();

    // one global cursor atomic per (block, nonzero bin)
    for (int i = t; i < nbins; i += 512) {
        int c = hbase[i];
        hbase[i] = (c > 0) ? atomicAdd(&binCur[i], c) : 0;
    }
    __syncthreads();

    // pass B: re-read edges, scatter packed (s,r_local) into grouped bin runs
    for (int e = base + t; e < end; e += 512) {
        int r = receivers[e];
        int s = senders[e];
        int bb = r >> BIN_SHIFT;
        int rank = atomicAdd(&hrank[bb], 1);
        int dest = hbase[bb] + rank;          // offset within bin
        if (dest < cap)                       // overflow clip (~1e-13)
            bins[(size_t)bb * cap + dest] = (s << BIN_SHIFT) | (r & (BIN_NODES - 1));
    }
}

__global__ void __launch_bounds__(256) bin_gather_kernel(
    const float4* __restrict__ posf4,
    const uint2* __restrict__ nfh,
    const int* __restrict__ bins,
    const int* __restrict__ binCur,
    const float* __restrict__ W,
    const float* __restrict__ Bias,
    float* __restrict__ out,
    int N, int cap)
{
    // packed per-edge record: (dx, dy, dz, sender-index-as-bits)
    __shared__ float4 ledge[CAP_LDS];
    __shared__ float4 lpos[HALF_NODES];    // receiver positions
    __shared__ int lhist[HALF_NODES];      // hist, then scatter cursor
    __shared__ int lscan[HALF_NODES];      // inclusive scan (end offsets)
    __shared__ int lstart[HALF_NODES];     // exclusive scan (start offsets)

    int t = threadIdx.x;
    int bin  = blockIdx.x >> 1;
    int half = blockIdx.x & 1;             // which 32-node half of the bin
    int node0 = (bin << BIN_SHIFT) + half * HALF_NODES;
    int gbase = bin * cap;

    int cnt = binCur[bin];                 // zero-based count
    if (cnt > cap) cnt = cap;

    if (t < HALF_NODES) {
        lhist[t] = 0;
        int n = node0 + t;
        lpos[t] = (n < N) ? posf4[n] : make_float4(0.f, 0.f, 0.f, 0.f);
    }
    __syncthreads();

    // pass 1: histogram local receivers belonging to this half
    for (int j = t; j < cnt; j += 256) {
        int rl = bins[gbase + j] & (BIN_NODES - 1);
        if ((rl >> 5) == half) atomicAdd(&lhist[rl & (HALF_NODES - 1)], 1);
    }
    __syncthreads();

    // 32-wide Hillis-Steele scan
    if (t < HALF_NODES) lscan[t] = lhist[t];
    __syncthreads();
    for (int off = 1; off < HALF_NODES; off <<= 1) {
        int v = (t < HALF_NODES && t >= off) ? lscan[t - off] : 0;
        __syncthreads();
        if (t < HALF_NODES) lscan[t] += v;
        __syncthreads();
    }
    if (t < HALF_NODES) { lstart[t] = lscan[t] - lhist[t]; lhist[t] = 0; }
    __syncthreads();

    // pass 2: scatter + per-edge direction precompute (once per edge)
    for (int j = t; j < cnt; j += 256) {
        int pk = bins[gbase + j];
        int rl = pk & (BIN_NODES - 1);
        if ((rl >> 5) != half) continue;
        int rl32 = rl & (HALF_NODES - 1);
        int s = pk >> BIN_SHIFT;
        int rank = atomicAdd(&lhist[rl32], 1);
        int dest = lstart[rl32] + rank;
        if (dest >= CAP_LDS) continue;     // half-overflow clip (~1e-30)
        float4 ps = posf4[s];
        float4 pr = lpos[rl32];
        float dx = pr.x - ps.x;
        float dy = pr.y - ps.y;
        float dz = pr.z - ps.z;
        float d2 = dx*dx + dy*dy + dz*dz;
        float inv = __builtin_amdgcn_rsqf(fmaxf(d2, 1e-18f));  // self-edge -> 0
        float4 rec;
        rec.x = dx * inv;
        rec.y = dy * inv;
        rec.z = dz * inv;
        rec.w = __int_as_float(s);         // raw bits; LDS moves are bit-exact
        ledge[dest] = rec;
    }
    __syncthreads();

    // register gather: thread (node, f); 2 nodes per thread; unroll x4
    float w[16];
#pragma unroll
    for (int i = 0; i < 16; ++i) w[i] = W[i];
    float b0 = Bias[0], b1 = Bias[1], b2 = Bias[2], b3 = Bias[3];
    const float INV_S3 = 0.5773502691896258f;
    const float INV_S2 = 0.7071067811865476f;
    const float sc = 1.0f / 32.0f;

    int f = t & 15;

    for (int nl = t >> 4; nl < HALF_NODES; nl += 16) {
        int n = node0 + nl;
        if (n >= N) break;
        int s0 = lstart[nl];
        int dcnt = lscan[nl] - s0;
        if (dcnt > CAP_LDS - s0) dcnt = CAP_LDS - s0;  // clip to stored records

        float sA = 0.f, sB = 0.f;
        float s1x = 0.f, s1y = 0.f, s1z = 0.f;
        float cc0 = 0.f, cc1 = 0.f, cc2 = 0.f;
        int j = 0;
        for (; j + 4 <= dcnt; j += 4) {
            float4 e0 = ledge[s0 + j + 0];
            float4 e1 = ledge[s0 + j + 1];
            float4 e2 = ledge[s0 + j + 2];
            float4 e3 = ledge[s0 + j + 3];
            int s_0 = __float_as_int(e0.w);
            int s_1 = __float_as_int(e1.w);
            int s_2 = __float_as_int(e2.w);
            int s_3 = __float_as_int(e3.w);
            // 4 independent 128B-row gathers in flight per 16-lane group
            uint2 u0 = nfh[(unsigned)(s_0 * F_DIM + f)];
            uint2 u1 = nfh[(unsigned)(s_1 * F_DIM + f)];
            uint2 u2 = nfh[(unsigned)(s_2 * F_DIM + f)];
            uint2 u3 = nfh[(unsigned)(s_3 * F_DIM + f)];
            edge_acc_d(e0.x, e0.y, e0.z, unpack_h4(u0),
                       sA, sB, s1x, s1y, s1z, cc0, cc1, cc2);
            edge_acc_d(e1.x, e1.y, e1.z, unpack_h4(u1),
                       sA, sB, s1x, s1y, s1z, cc0, cc1, cc2);
            edge_acc_d(e2.x, e2.y, e2.z, unpack_h4(u2),
                       sA, sB, s1x, s1y, s1z, cc0, cc1, cc2);
            edge_acc_d(e3.x, e3.y, e3.z, unpack_h4(u3),
                       sA, sB, s1x, s1y, s1z, cc0, cc1, cc2);
        }
        for (; j < dcnt; ++j) {
            float4 e0 = ledge[s0 + j];
            int s = __float_as_int(e0.w);
            uint2 u = nfh[(unsigned)(s * F_DIM + f)];
            edge_acc_d(e0.x, e0.y, e0.z, unpack_h4(u),
                       sA, sB, s1x, s1y, s1z, cc0, cc1, cc2);
        }

        // apply deferred scales once
        float a0 = (sA  + INV_S3 * sB)  * sc;
        float a1 = (s1x + INV_S2 * cc0) * sc;
        float a2 = (s1y + INV_S2 * cc1) * sc;
        float a3 = (s1z + INV_S2 * cc2) * sc;
        float4 o;
        o.x = a0*w[0] + a1*w[4] + a2*w[8]  + a3*w[12] + b0;
        o.y = a0*w[1] + a1*w[5] + a2*w[9]  + a3*w[13] + b1;
        o.z = a0*w[2] + a1*w[6] + a2*w[10] + a3*w[14] + b2;
        o.w = a0*w[3] + a1*w[7] + a2*w[11] + a3*w[15] + b3;
        ((float4*)out)[(size_t)n * F_DIM + f] = o;      // 256B per 16-lane group
    }
}

// ---------------- fallback: exact CSR path ----------------------------------
__global__ void __launch_bounds__(256) hist_kernel(
    const int* __restrict__ receivers, int* __restrict__ deg,
    int* __restrict__ rank, int E)
{
    int e = blockIdx.x * blockDim.x + threadIdx.x;
    if (e >= E) return;
    rank[e] = atomicAdd(&deg[receivers[e]], 1);
}

__global__ void __launch_bounds__(256) alloc_kernel(
    const int* __restrict__ deg, int* __restrict__ start,
    int* __restrict__ cursor, int N)
{
    __shared__ int tmp[256];
    __shared__ int base;
    int t = threadIdx.x;
    int n = blockIdx.x * blockDim.x + t;
    int v = (n < N) ? deg[n] : 0;
    tmp[t] = v;
    __syncthreads();
    for (int off = 1; off < 256; off <<= 1) {
        int x = (t >= off) ? tmp[t - off] : 0;
        __syncthreads();
        tmp[t] += x;
        __syncthreads();
    }
    int incl = tmp[t];
    if (t == 255) base = atomicAdd(cursor, incl);
    __syncthreads();
    if (n < N) start[n] = base + incl - v;
}

__global__ void __launch_bounds__(256) scatter_kernel(
    const int* __restrict__ senders, const int* __restrict__ receivers,
    const int* __restrict__ rank, const int* __restrict__ start,
    int* __restrict__ csr_s, int E)
{
    int e = blockIdx.x * blockDim.x + threadIdx.x;
    if (e >= E) return;
    csr_s[start[receivers[e]] + rank[e]] = senders[e];
}

__global__ void __launch_bounds__(256) gather_kernel(
    const float* __restrict__ pos,
    const float* __restrict__ nf,
    const int* __restrict__ csr_s,
    const int* __restrict__ start,
    const int* __restrict__ deg,
    const float* __restrict__ W,
    const float* __restrict__ b,
    float* __restrict__ out,
    int N)
{
    const float INV_S3 = 0.5773502691896258f;
    const float INV_S2 = 0.7071067811865476f;

    int tid = blockIdx.x * blockDim.x + threadIdx.x;
    int n = tid >> 4;
    if (n >= N) return;
    int f = tid & 15;

    float rx = pos[3*n], ry = pos[3*n+1], rz = pos[3*n+2];
    int s0 = start[n];
    int dcnt = deg[n];
    float a0 = 0.f, a1 = 0.f, a2 = 0.f, a3 = 0.f;
    const float4* nf4 = (const float4*)nf;

    for (int j = 0; j < dcnt; ++j) {
        int s = csr_s[s0 + j];
        float dx = rx - pos[3*s], dy = ry - pos[3*s+1], dz = rz - pos[3*s+2];
        float d2 = dx*dx + dy*dy + dz*dz;
        float inv = __builtin_amdgcn_rsqf(fmaxf(d2, 1e-18f));
        dx *= inv; dy *= inv; dz *= inv;
        float4 x = nf4[(unsigned)(s * F_DIM + f)];
        float dot = x.y*dx + x.z*dy + x.w*dz;
        a0 += x.x + dot * INV_S3;
        float c0 = x.z*dz - x.w*dy, c1 = x.w*dx - x.y*dz, c2 = x.y*dy - x.z*dx;
        a1 += x.x*dx + x.y + c0 * INV_S2;
        a2 += x.x*dy + x.z + c1 * INV_S2;
        a3 += x.x*dz + x.w + c2 * INV_S2;
    }
    const float sc = 1.0f / 32.0f;
    a0 *= sc; a1 *= sc; a2 *= sc; a3 *= sc;
    float4 o;
    o.x = a0*W[0] + a1*W[4] + a2*W[8]  + a3*W[12] + b[0];
    o.y = a0*W[1] + a1*W[5] + a2*W[9]  + a3*W[13] + b[1];
    o.z = a0*W[2] + a1*W[6] + a2*W[10] + a3*W[14] + b[2];
    o.w = a0*W[3] + a1*W[7] + a2*W[11] + a3*W[15] + b[3];
    ((float4*)out)[tid] = o;
}

extern "C" void kernel_launch(void* const* d_in, const int* in_sizes, int n_in,
                              void* d_out, int out_size, void* d_ws, size_t ws_size,
                              hipStream_t stream)
{
    const float* pos       = (const float*)d_in[0];
    const float* nf        = (const float*)d_in[1];
    const float* W         = (const float*)d_in[2];
    const float* b         = (const float*)d_in[3];
    const int*   senders   = (const int*)d_in[4];
    const int*   receivers = (const int*)d_in[5];

    int N = in_sizes[0] / 3;
    int E = in_sizes[4];
    float* out = (float*)d_out;
    const int blk = 256;

    int nbins = (N + BIN_NODES - 1) >> BIN_SHIFT;
    int cap   = E / nbins + 453;   // mean + ~10 sigma (Poisson)
    // ws: [posf4(16N)][nfh(8*N*F_DIM)][binCur(nbins)][bins(nbins*cap)]
    size_t need = (size_t)N * 16 + (size_t)N * F_DIM * 8
                + ((size_t)nbins + (size_t)nbins * cap) * 4;

    if (nbins <= MAXBINS && ws_size >= need) {
        float4* posf4 = (float4*)d_ws;
        uint2*  nfh   = (uint2*)(posf4 + N);
        int* binCur = (int*)(nfh + (size_t)N * F_DIM);
        int* bins   = binCur + nbins;

        int total = N * F_DIM;
        pack_kernel<<<(total + blk - 1) / blk, blk, 0, stream>>>(
            pos, nf, posf4, nfh, binCur, N, nbins);
        build_bins_kernel<<<(E + CHUNK - 1) / CHUNK, 512, 0, stream>>>(
            senders, receivers, binCur, bins, nbins, cap, E);
        bin_gather_kernel<<<nbins * 2, blk, 0, stream>>>(
            posf4, nfh, bins, binCur, W, b, out, N, cap);
    } else {
        // ws layout: [cursor(1)][deg(N)][start(N)][rank(E)][csr_s(E)]
        int* cursor = (int*)d_ws;
        int* deg    = cursor + 1;
        int* start  = deg + N;
        int* rank   = start + N;
        int* csr_s  = rank + E;

        hipMemsetAsync(cursor, 0, (size_t)(1 + N) * sizeof(int), stream);
        hist_kernel<<<(E + blk - 1) / blk, blk, 0, stream>>>(receivers, deg, rank, E);
        alloc_kernel<<<(N + blk - 1) / blk, blk, 0, stream>>>(deg, start, cursor, N);
        scatter_kernel<<<(E + blk - 1) / blk, blk, 0, stream>>>(
            senders, receivers, rank, start, csr_s, E);
        long total = (long)N * F_DIM;
        gather_kernel<<<(unsigned)((total + blk - 1) / blk), blk, 0, stream>>>(
            pos, nf, csr_s, start, deg, W, b, out, N);
    }
}

// Round 13
// 243.713 us; speedup vs baseline: 1.0480x; 1.0480x over previous
//
#include <hip/hip_runtime.h>
#include <hip/hip_fp16.h>

// e3jLayer: per-edge equivariant tensor product + segment-sum + linear.
// Round 21 = R20 + fp16-compressed LDS edge records (occupancy, zero extra bytes).
//   R20: gather 88.4us, FETCH 197.5MB @2.57TB/s (=77us pure fetch), occ 48%
//   (LDS 23.5KB -> 6 blocks/CU). R19 proved occupancy-via-more-blocks costs
//   rescan bytes; this round raises occupancy by SHRINKING the record instead:
//   (dx,dy,dz) stored as fp16x3 (h2(dx,dy) + h(dz)) + int sender = 12B/edge
//   (was 16B float4). LDS 23.5 -> ~17.8KB -> 8 blocks/CU (32 waves, 100%).
//   Dir fp16 error ~1-2e-3 through the deg~32 mean — below the fp16-nf step
//   already absorbed (absmax 0.0078 passing). Build/pack = R15/R20 config
//   (512t CHUNK8192 two-pass; 5 builds tried, grouped-run two-pass is best;
//   totals carry +/-15us cross-container noise).
// Fallback: exact 3-kernel CSR path if sizing fails.

#define F_DIM 16
#define BIN_SHIFT 6
#define BIN_NODES (1 << BIN_SHIFT)   // 64 receivers per bin
#define HALF_NODES (BIN_NODES / 2)   // 32 per gather block
#define CHUNK 8192                   // edges per build block
#define CAP_LDS 1408                 // max edges per bin-half in gather LDS
#define MAXBINS 2048

__device__ __forceinline__ float4 unpack_h4(uint2 u)
{
    __half2 h01 = *reinterpret_cast<__half2*>(&u.x);
    __half2 h23 = *reinterpret_cast<__half2*>(&u.y);
    float2 a = __half22float2(h01);
    float2 b = __half22float2(h23);
    return make_float4(a.x, a.y, b.x, b.y);
}

// accumulate one edge with DEFERRED scaling: no INV_S3/INV_S2 mults here.
__device__ __forceinline__ void edge_acc_d(
    float dx, float dy, float dz, const float4& fx,
    float& sA, float& sB, float& s1x, float& s1y, float& s1z,
    float& c0, float& c1, float& c2)
{
    sA += fx.x;
    sB += fx.y*dx + fx.z*dy + fx.w*dz;
    s1x += __builtin_fmaf(fx.x, dx, fx.y);
    s1y += __builtin_fmaf(fx.x, dy, fx.z);
    s1z += __builtin_fmaf(fx.x, dz, fx.w);
    c0 += fx.z*dz - fx.w*dy;
    c1 += fx.w*dx - fx.y*dz;
    c2 += fx.y*dy - fx.z*dx;
}

// ---- pack: nf->fp16 rows, pos->float4, zero binCur (one dispatch) ----------
__global__ void __launch_bounds__(256) pack_kernel(
    const float* __restrict__ pos, const float* __restrict__ nf,
    float4* __restrict__ posf4, uint2* __restrict__ nfh,
    int* __restrict__ binCur, int N, int nbins)
{
    int tid = blockIdx.x * blockDim.x + threadIdx.x;
    int total = N * F_DIM;
    if (tid < total) {
        float4 q = ((const float4*)nf)[tid];
        __half2 h01 = __floats2half2_rn(q.x, q.y);
        __half2 h23 = __floats2half2_rn(q.z, q.w);
        uint2 u;
        u.x = *reinterpret_cast<unsigned*>(&h01);
        u.y = *reinterpret_cast<unsigned*>(&h23);
        nfh[tid] = u;
    }
    if (tid < N)
        posf4[tid] = make_float4(pos[3*tid], pos[3*tid+1], pos[3*tid+2], 0.f);
    if (tid < nbins)
        binCur[tid] = 0;
}

// ---- two-pass grouped-run build @512t (R15 config) -------------------------
__global__ void __launch_bounds__(512) build_bins_kernel(
    const int* __restrict__ senders, const int* __restrict__ receivers,
    int* __restrict__ binCur, int* __restrict__ bins,
    int nbins, int cap, int E)
{
    __shared__ int hbase[MAXBINS];   // count, then base offset within bin
    __shared__ int hrank[MAXBINS];   // scatter tickets
    int t = threadIdx.x;
    for (int i = t; i < nbins; i += 512) { hbase[i] = 0; hrank[i] = 0; }
    __syncthreads();

    int base = blockIdx.x * CHUNK;
    int end  = base + CHUNK; if (end > E) end = E;
    if (base >= end) return;

    // pass A: histogram receiver bins
    for (int e = base + t; e < end; e += 512)
        atomicAdd(&hbase[((unsigned)receivers[e]) >> BIN_SHIFT], 1);
    __syncthreads();

    // one global cursor atomic per (block, nonzero bin)
    for (int i = t; i < nbins; i += 512) {
        int c = hbase[i];
        hbase[i] = (c > 0) ? atomicAdd(&binCur[i], c) : 0;
    }
    __syncthreads();

    // pass B: re-read edges, scatter packed (s,r_local) into grouped bin runs
    for (int e = base + t; e < end; e += 512) {
        int r = receivers[e];
        int s = senders[e];
        int bb = r >> BIN_SHIFT;
        int rank = atomicAdd(&hrank[bb], 1);
        int dest = hbase[bb] + rank;          // offset within bin
        if (dest < cap)                       // overflow clip (~1e-13)
            bins[(size_t)bb * cap + dest] = (s << BIN_SHIFT) | (r & (BIN_NODES - 1));
    }
}

__global__ void __launch_bounds__(256) bin_gather_kernel(
    const float4* __restrict__ posf4,
    const uint2* __restrict__ nfh,
    const int* __restrict__ bins,
    const int* __restrict__ binCur,
    const float* __restrict__ W,
    const float* __restrict__ Bias,
    float* __restrict__ out,
    int N, int cap)
{
    // compressed per-edge record: sender int + fp16x3 unit direction (12B)
    __shared__ int   lcsr[CAP_LDS];        // sender index
    __shared__ uint2 ldir[CAP_LDS];        // .x = h2(dx,dy), .y = h(dz) low16
    __shared__ float4 lpos[HALF_NODES];    // receiver positions
    __shared__ int lhist[HALF_NODES];      // hist, then scatter cursor
    __shared__ int lscan[HALF_NODES];      // inclusive scan (end offsets)
    __shared__ int lstart[HALF_NODES];     // exclusive scan (start offsets)

    int t = threadIdx.x;
    int bin  = blockIdx.x >> 1;
    int half = blockIdx.x & 1;             // which 32-node half of the bin
    int node0 = (bin << BIN_SHIFT) + half * HALF_NODES;
    int gbase = bin * cap;

    int cnt = binCur[bin];                 // zero-based count
    if (cnt > cap) cnt = cap;

    if (t < HALF_NODES) {
        lhist[t] = 0;
        int n = node0 + t;
        lpos[t] = (n < N) ? posf4[n] : make_float4(0.f, 0.f, 0.f, 0.f);
    }
    __syncthreads();

    // pass 1: histogram local receivers belonging to this half
    for (int j = t; j < cnt; j += 256) {
        int rl = bins[gbase + j] & (BIN_NODES - 1);
        if ((rl >> 5) == half) atomicAdd(&lhist[rl & (HALF_NODES - 1)], 1);
    }
    __syncthreads();

    // 32-wide Hillis-Steele scan
    if (t < HALF_NODES) lscan[t] = lhist[t];
    __syncthreads();
    for (int off = 1; off < HALF_NODES; off <<= 1) {
        int v = (t < HALF_NODES && t >= off) ? lscan[t - off] : 0;
        __syncthreads();
        if (t < HALF_NODES) lscan[t] += v;
        __syncthreads();
    }
    if (t < HALF_NODES) { lstart[t] = lscan[t] - lhist[t]; lhist[t] = 0; }
    __syncthreads();

    // pass 2: scatter + per-edge direction precompute (f32 math, fp16 store)
    for (int j = t; j < cnt; j += 256) {
        int pk = bins[gbase + j];
        int rl = pk & (BIN_NODES - 1);
        if ((rl >> 5) != half) continue;
        int rl32 = rl & (HALF_NODES - 1);
        int s = pk >> BIN_SHIFT;
        int rank = atomicAdd(&lhist[rl32], 1);
        int dest = lstart[rl32] + rank;
        if (dest >= CAP_LDS) continue;     // half-overflow clip (~1e-30)
        float4 ps = posf4[s];
        float4 pr = lpos[rl32];
        float dx = pr.x - ps.x;
        float dy = pr.y - ps.y;
        float dz = pr.z - ps.z;
        float d2 = dx*dx + dy*dy + dz*dz;
        float inv = __builtin_amdgcn_rsqf(fmaxf(d2, 1e-18f));  // self-edge -> 0
        __half2 hxy = __floats2half2_rn(dx * inv, dy * inv);
        __half  hz  = __float2half_rn(dz * inv);
        uint2 d;
        d.x = *reinterpret_cast<unsigned*>(&hxy);
        d.y = (unsigned)*reinterpret_cast<unsigned short*>(&hz);
        ldir[dest] = d;
        lcsr[dest] = s;
    }
    __syncthreads();

    // register gather: thread (node, f); 2 nodes per thread; unroll x4
    float w[16];
#pragma unroll
    for (int i = 0; i < 16; ++i) w[i] = W[i];
    float b0 = Bias[0], b1 = Bias[1], b2 = Bias[2], b3 = Bias[3];
    const float INV_S3 = 0.5773502691896258f;
    const float INV_S2 = 0.7071067811865476f;
    const float sc = 1.0f / 32.0f;

    int f = t & 15;

    for (int nl = t >> 4; nl < HALF_NODES; nl += 16) {
        int n = node0 + nl;
        if (n >= N) break;
        int s0 = lstart[nl];
        int dcnt = lscan[nl] - s0;
        if (dcnt > CAP_LDS - s0) dcnt = CAP_LDS - s0;  // clip to stored records

        float sA = 0.f, sB = 0.f;
        float s1x = 0.f, s1y = 0.f, s1z = 0.f;
        float cc0 = 0.f, cc1 = 0.f, cc2 = 0.f;
        int j = 0;
        for (; j + 4 <= dcnt; j += 4) {
            int s_0 = lcsr[s0 + j + 0];
            int s_1 = lcsr[s0 + j + 1];
            int s_2 = lcsr[s0 + j + 2];
            int s_3 = lcsr[s0 + j + 3];
            uint2 d0 = ldir[s0 + j + 0];
            uint2 d1 = ldir[s0 + j + 1];
            uint2 d2 = ldir[s0 + j + 2];
            uint2 d3 = ldir[s0 + j + 3];
            // 4 independent 128B-row gathers in flight per 16-lane group
            uint2 u0 = nfh[(unsigned)(s_0 * F_DIM + f)];
            uint2 u1 = nfh[(unsigned)(s_1 * F_DIM + f)];
            uint2 u2 = nfh[(unsigned)(s_2 * F_DIM + f)];
            uint2 u3 = nfh[(unsigned)(s_3 * F_DIM + f)];
            {
                float2 xy = __half22float2(*reinterpret_cast<__half2*>(&d0.x));
                unsigned short hz = (unsigned short)d0.y;
                float dz = __half2float(*reinterpret_cast<__half*>(&hz));
                edge_acc_d(xy.x, xy.y, dz, unpack_h4(u0),
                           sA, sB, s1x, s1y, s1z, cc0, cc1, cc2);
            }
            {
                float2 xy = __half22float2(*reinterpret_cast<__half2*>(&d1.x));
                unsigned short hz = (unsigned short)d1.y;
                float dz = __half2float(*reinterpret_cast<__half*>(&hz));
                edge_acc_d(xy.x, xy.y, dz, unpack_h4(u1),
                           sA, sB, s1x, s1y, s1z, cc0, cc1, cc2);
            }
            {
                float2 xy = __half22float2(*reinterpret_cast<__half2*>(&d2.x));
                unsigned short hz = (unsigned short)d2.y;
                float dz = __half2float(*reinterpret_cast<__half*>(&hz));
                edge_acc_d(xy.x, xy.y, dz, unpack_h4(u2),
                           sA, sB, s1x, s1y, s1z, cc0, cc1, cc2);
            }
            {
                float2 xy = __half22float2(*reinterpret_cast<__half2*>(&d3.x));
                unsigned short hz = (unsigned short)d3.y;
                float dz = __half2float(*reinterpret_cast<__half*>(&hz));
                edge_acc_d(xy.x, xy.y, dz, unpack_h4(u3),
                           sA, sB, s1x, s1y, s1z, cc0, cc1, cc2);
            }
        }
        for (; j < dcnt; ++j) {
            int s = lcsr[s0 + j];
            uint2 d0 = ldir[s0 + j];
            uint2 u = nfh[(unsigned)(s * F_DIM + f)];
            float2 xy = __half22float2(*reinterpret_cast<__half2*>(&d0.x));
            unsigned short hz = (unsigned short)d0.y;
            float dz = __half2float(*reinterpret_cast<__half*>(&hz));
            edge_acc_d(xy.x, xy.y, dz, unpack_h4(u),
                       sA, sB, s1x, s1y, s1z, cc0, cc1, cc2);
        }

        // apply deferred scales once
        float a0 = (sA  + INV_S3 * sB)  * sc;
        float a1 = (s1x + INV_S2 * cc0) * sc;
        float a2 = (s1y + INV_S2 * cc1) * sc;
        float a3 = (s1z + INV_S2 * cc2) * sc;
        float4 o;
        o.x = a0*w[0] + a1*w[4] + a2*w[8]  + a3*w[12] + b0;
        o.y = a0*w[1] + a1*w[5] + a2*w[9]  + a3*w[13] + b1;
        o.z = a0*w[2] + a1*w[6] + a2*w[10] + a3*w[14] + b2;
        o.w = a0*w[3] + a1*w[7] + a2*w[11] + a3*w[15] + b3;
        ((float4*)out)[(size_t)n * F_DIM + f] = o;      // 256B per 16-lane group
    }
}

// ---------------- fallback: exact CSR path ----------------------------------
__global__ void __launch_bounds__(256) hist_kernel(
    const int* __restrict__ receivers, int* __restrict__ deg,
    int* __restrict__ rank, int E)
{
    int e = blockIdx.x * blockDim.x + threadIdx.x;
    if (e >= E) return;
    rank[e] = atomicAdd(&deg[receivers[e]], 1);
}

__global__ void __launch_bounds__(256) alloc_kernel(
    const int* __restrict__ deg, int* __restrict__ start,
    int* __restrict__ cursor, int N)
{
    __shared__ int tmp[256];
    __shared__ int base;
    int t = threadIdx.x;
    int n = blockIdx.x * blockDim.x + t;
    int v = (n < N) ? deg[n] : 0;
    tmp[t] = v;
    __syncthreads();
    for (int off = 1; off < 256; off <<= 1) {
        int x = (t >= off) ? tmp[t - off] : 0;
        __syncthreads();
        tmp[t] += x;
        __syncthreads();
    }
    int incl = tmp[t];
    if (t == 255) base = atomicAdd(cursor, incl);
    __syncthreads();
    if (n < N) start[n] = base + incl - v;
}

__global__ void __launch_bounds__(256) scatter_kernel(
    const int* __restrict__ senders, const int* __restrict__ receivers,
    const int* __restrict__ rank, const int* __restrict__ start,
    int* __restrict__ csr_s, int E)
{
    int e = blockIdx.x * blockDim.x + threadIdx.x;
    if (e >= E) return;
    csr_s[start[receivers[e]] + rank[e]] = senders[e];
}

__global__ void __launch_bounds__(256) gather_kernel(
    const float* __restrict__ pos,
    const float* __restrict__ nf,
    const int* __restrict__ csr_s,
    const int* __restrict__ start,
    const int* __restrict__ deg,
    const float* __restrict__ W,
    const float* __restrict__ b,
    float* __restrict__ out,
    int N)
{
    const float INV_S3 = 0.5773502691896258f;
    const float INV_S2 = 0.7071067811865476f;

    int tid = blockIdx.x * blockDim.x + threadIdx.x;
    int n = tid >> 4;
    if (n >= N) return;
    int f = tid & 15;

    float rx = pos[3*n], ry = pos[3*n+1], rz = pos[3*n+2];
    int s0 = start[n];
    int dcnt = deg[n];
    float a0 = 0.f, a1 = 0.f, a2 = 0.f, a3 = 0.f;
    const float4* nf4 = (const float4*)nf;

    for (int j = 0; j < dcnt; ++j) {
        int s = csr_s[s0 + j];
        float dx = rx - pos[3*s], dy = ry - pos[3*s+1], dz = rz - pos[3*s+2];
        float d2 = dx*dx + dy*dy + dz*dz;
        float inv = __builtin_amdgcn_rsqf(fmaxf(d2, 1e-18f));
        dx *= inv; dy *= inv; dz *= inv;
        float4 x = nf4[(unsigned)(s * F_DIM + f)];
        float dot = x.y*dx + x.z*dy + x.w*dz;
        a0 += x.x + dot * INV_S3;
        float c0 = x.z*dz - x.w*dy, c1 = x.w*dx - x.y*dz, c2 = x.y*dy - x.z*dx;
        a1 += x.x*dx + x.y + c0 * INV_S2;
        a2 += x.x*dy + x.z + c1 * INV_S2;
        a3 += x.x*dz + x.w + c2 * INV_S2;
    }
    const float sc = 1.0f / 32.0f;
    a0 *= sc; a1 *= sc; a2 *= sc; a3 *= sc;
    float4 o;
    o.x = a0*W[0] + a1*W[4] + a2*W[8]  + a3*W[12] + b[0];
    o.y = a0*W[1] + a1*W[5] + a2*W[9]  + a3*W[13] + b[1];
    o.z = a0*W[2] + a1*W[6] + a2*W[10] + a3*W[14] + b[2];
    o.w = a0*W[3] + a1*W[7] + a2*W[11] + a3*W[15] + b[3];
    ((float4*)out)[tid] = o;
}

extern "C" void kernel_launch(void* const* d_in, const int* in_sizes, int n_in,
                              void* d_out, int out_size, void* d_ws, size_t ws_size,
                              hipStream_t stream)
{
    const float* pos       = (const float*)d_in[0];
    const float* nf        = (const float*)d_in[1];
    const float* W         = (const float*)d_in[2];
    const float* b         = (const float*)d_in[3];
    const int*   senders   = (const int*)d_in[4];
    const int*   receivers = (const int*)d_in[5];

    int N = in_sizes[0] / 3;
    int E = in_sizes[4];
    float* out = (float*)d_out;
    const int blk = 256;

    int nbins = (N + BIN_NODES - 1) >> BIN_SHIFT;
    int cap   = E / nbins + 453;   // mean + ~10 sigma (Poisson)
    // ws: [posf4(16N)][nfh(8*N*F_DIM)][binCur(nbins)][bins(nbins*cap)]
    size_t need = (size_t)N * 16 + (size_t)N * F_DIM * 8
                + ((size_t)nbins + (size_t)nbins * cap) * 4;

    if (nbins <= MAXBINS && ws_size >= need) {
        float4* posf4 = (float4*)d_ws;
        uint2*  nfh   = (uint2*)(posf4 + N);
        int* binCur = (int*)(nfh + (size_t)N * F_DIM);
        int* bins   = binCur + nbins;

        int total = N * F_DIM;
        pack_kernel<<<(total + blk - 1) / blk, blk, 0, stream>>>(
            pos, nf, posf4, nfh, binCur, N, nbins);
        build_bins_kernel<<<(E + CHUNK - 1) / CHUNK, 512, 0, stream>>>(
            senders, receivers, binCur, bins, nbins, cap, E);
        bin_gather_kernel<<<nbins * 2, blk, 0, stream>>>(
            posf4, nfh, bins, binCur, W, b, out, N, cap);
    } else {
        // ws layout: [cursor(1)][deg(N)][start(N)][rank(E)][csr_s(E)]
        int* cursor = (int*)d_ws;
        int* deg    = cursor + 1;
        int* start  = deg + N;
        int* rank   = start + N;
        int* csr_s  = rank + E;

        hipMemsetAsync(cursor, 0, (size_t)(1 + N) * sizeof(int), stream);
        hist_kernel<<<(E + blk - 1) / blk, blk, 0, stream>>>(receivers, deg, rank, E);
        alloc_kernel<<<(N + blk - 1) / blk, blk, 0, stream>>>(deg, start, cursor, N);
        scatter_kernel<<<(E + blk - 1) / blk, blk, 0, stream>>>(
            senders, receivers, rank, start, csr_s, E);
        long total = (long)N * F_DIM;
        gather_kernel<<<(unsigned)((total + blk - 1) / blk), blk, 0, stream>>>(
            pos, nf, csr_s, start, deg, W, b, out, N);
    }
}